// Round 4
// baseline (494.906 us; speedup 1.0000x reference)
//
#include <hip/hip_runtime.h>
#include <math.h>

#define Bb 2
#define Nn 32768
#define Cc 128
#define Ff 128
#define LL 4
#define SKN 128
#define TWOPI 6.283185307179586f

typedef __attribute__((ext_vector_type(8))) short short8;
typedef __attribute__((ext_vector_type(4))) float float4v;
typedef unsigned short ushort_t;
typedef unsigned int uint_t;

union frag_cast { short8 s; uint_t u[4]; };
union vec8 { float4v v[2]; float s[8]; };

__device__ inline uint_t asu(float f) { union { float f; uint_t u; } x; x.f = f; return x.u; }
__device__ inline float asf(uint_t u) { union { uint_t u; float f; } x; x.u = u; return x.f; }
// pack: low16 = bf16-trunc(v0), high16 = bf16-trunc(v1)
__device__ inline uint_t pack_hi(float v0, float v1) { return (asu(v0) >> 16) | (asu(v1) & 0xffff0000u); }
// exact residual after bf16 truncation
__device__ inline float resid(float v) { return v - asf(asu(v) & 0xffff0000u); }

// ---------------- prep: transpose x,y -> [b][d][n] planes
__global__ __launch_bounds__(256) void prep_xt(const float* __restrict__ x,
                                               const float* __restrict__ y,
                                               float* __restrict__ xT,
                                               float* __restrict__ yT) {
    int i = blockIdx.x * 256 + threadIdx.x;        // b*Nn + n
    int b = i >> 15, n = i & 32767;
    const float* xp = x + (size_t)i * 3;
    const float* yp = y + (size_t)i * 3;
    size_t base = ((size_t)(b * 3) << 15) + n;
    xT[base] = xp[0]; xT[base + (1 << 15)] = xp[1]; xT[base + (2 << 15)] = xp[2];
    yT[base] = yp[0]; yT[base + (1 << 15)] = yp[1]; yT[base + (2 << 15)] = yp[2];
}

// ---------------- in projection -> hfT[b][c][n]
__global__ __launch_bounds__(256) void in_proj(const float* __restrict__ a,
                                               const float* __restrict__ w,
                                               const float* __restrict__ bias,
                                               float* __restrict__ hfT) {
    int idx = blockIdx.x * 256 + threadIdx.x;      // b*C*N + c*N + n
    int n = idx & 32767;
    int c = (idx >> 15) & 127;
    int b = idx >> 22;
    const float* ap = a + (((size_t)(b << 15)) + n) * 4;
    float s = bias[c];
#pragma unroll
    for (int i = 0; i < 4; ++i) s += ap[i] * w[i * Cc + c];
    hfT[idx] = s;
}

// ---------------- forward transform: barrier-free, zero-LDS MFMA.
// Spart[b,h,sk][c][f] = sum_{n in chunk} hfT[b][c][n] * trig_h(x[n]·k2pi[f])
__global__ __launch_bounds__(256) void fwd_bf(const float* __restrict__ hfT,
                                              const float* __restrict__ xT,
                                              const float* __restrict__ freqs,
                                              float* __restrict__ Spart) {
    const int sk = blockIdx.x, h = blockIdx.y, b = blockIdx.z;
    const int n0 = sk * (Nn / SKN);                // 256-point chunk
    const int tid = threadIdx.x, lane = tid & 63, wave = tid >> 6;
    const int wm = wave & 1, wn = wave >> 1;       // waves: 2 c-halves x 2 f-halves
    const int fr = lane & 15, kg = lane >> 4;

    // per-lane fixed frequencies (pre-scaled by 2pi) for the 4 B-frag columns
    float kx[4], ky[4], kz[4];
#pragma unroll
    for (int ni = 0; ni < 4; ++ni) {
        int f = wn * 64 + ni * 16 + fr;
        kx[ni] = TWOPI * freqs[f * 3 + 0];
        ky[ni] = TWOPI * freqs[f * 3 + 1];
        kz[ni] = TWOPI * freqs[f * 3 + 2];
    }

    const float* xb = xT + ((size_t)(b * 3) << 15);
    const float* hb = hfT + ((size_t)(b * 128) << 15);

    float4v acc[4][4];
#pragma unroll
    for (int mi = 0; mi < 4; ++mi)
#pragma unroll
        for (int ni = 0; ni < 4; ++ni) acc[mi][ni] = (float4v){0.f, 0.f, 0.f, 0.f};

    for (int kt = 0; kt < Nn / SKN; kt += 32) {
        const int nbase = n0 + kt + kg * 8;        // this lane's 8 k-points
        vec8 X0, X1, X2;
        X0.v[0] = *(const float4v*)(xb + nbase);
        X0.v[1] = *(const float4v*)(xb + nbase + 4);
        X1.v[0] = *(const float4v*)(xb + (1 << 15) + nbase);
        X1.v[1] = *(const float4v*)(xb + (1 << 15) + nbase + 4);
        X2.v[0] = *(const float4v*)(xb + (2 << 15) + nbase);
        X2.v[1] = *(const float4v*)(xb + (2 << 15) + nbase + 4);

        frag_cast bh[4], bl[4];
#pragma unroll
        for (int ni = 0; ni < 4; ++ni)
#pragma unroll
            for (int q = 0; q < 4; ++q) {
                float a0 = X0.s[2 * q] * kx[ni] + X1.s[2 * q] * ky[ni] + X2.s[2 * q] * kz[ni];
                float a1 = X0.s[2 * q + 1] * kx[ni] + X1.s[2 * q + 1] * ky[ni] + X2.s[2 * q + 1] * kz[ni];
                float v0 = h ? __sinf(a0) : __cosf(a0);
                float v1 = h ? __sinf(a1) : __cosf(a1);
                bh[ni].u[q] = pack_hi(v0, v1);
                bl[ni].u[q] = pack_hi(resid(v0), resid(v1));
            }

#pragma unroll
        for (int mi = 0; mi < 4; ++mi) {
            const float* hp = hb + (((size_t)(wm * 64 + mi * 16 + fr)) << 15) + nbase;
            float4v h0 = *(const float4v*)hp;
            float4v h1 = *(const float4v*)(hp + 4);
            frag_cast ah, al;
            ah.u[0] = pack_hi(h0[0], h0[1]); ah.u[1] = pack_hi(h0[2], h0[3]);
            ah.u[2] = pack_hi(h1[0], h1[1]); ah.u[3] = pack_hi(h1[2], h1[3]);
            al.u[0] = pack_hi(resid(h0[0]), resid(h0[1])); al.u[1] = pack_hi(resid(h0[2]), resid(h0[3]));
            al.u[2] = pack_hi(resid(h1[0]), resid(h1[1])); al.u[3] = pack_hi(resid(h1[2]), resid(h1[3]));
#pragma unroll
            for (int ni = 0; ni < 4; ++ni) {
                acc[mi][ni] = __builtin_amdgcn_mfma_f32_16x16x32_bf16(ah.s, bh[ni].s, acc[mi][ni], 0, 0, 0);
                acc[mi][ni] = __builtin_amdgcn_mfma_f32_16x16x32_bf16(ah.s, bl[ni].s, acc[mi][ni], 0, 0, 0);
                acc[mi][ni] = __builtin_amdgcn_mfma_f32_16x16x32_bf16(al.s, bh[ni].s, acc[mi][ni], 0, 0, 0);
            }
        }
    }

    float* op = Spart + ((size_t)((b * 2 + h) * SKN + sk)) * 16384;
#pragma unroll
    for (int mi = 0; mi < 4; ++mi)
#pragma unroll
        for (int ni = 0; ni < 4; ++ni)
#pragma unroll
            for (int r = 0; r < 4; ++r) {
                int c = wm * 64 + mi * 16 + kg * 4 + r;
                int f = wn * 64 + ni * 16 + fr;
                op[c * 128 + f] = acc[mi][ni][r];
            }
}

// ---------------- reduce split-K partials: S[bh][c][f] = sum_sk Spart
__global__ __launch_bounds__(256) void reduce_kernel(const float* __restrict__ Spart,
                                                     float* __restrict__ S) {
    int idx = blockIdx.x * 256 + threadIdx.x;
    int bh = idx >> 14, cf = idx & 16383;
    const float* p = Spart + (size_t)bh * SKN * 16384 + cf;
    float s = 0.0f;
#pragma unroll 8
    for (int k = 0; k < SKN; ++k) s += p[(size_t)k * 16384];
    S[idx] = s;
}

// ---------------- channel mixing -> packed bf16 hi/lo G planes (both b per block, W read once)
__global__ __launch_bounds__(256) void mix_kernel(const float* __restrict__ S,
                                                  const float* __restrict__ Wre,
                                                  const float* __restrict__ Wim,
                                                  uint_t* __restrict__ Gh,
                                                  uint_t* __restrict__ Gl) {
    __shared__ float Stile[4][128][16];            // [b*2+h][c][f-local], 32 KB
    const int ot = blockIdx.x;                     // 32 tiles of 4 o
    const int ft = blockIdx.y;                     // 8 tiles of 16 f
    const int tid = threadIdx.x;
    const int fl = tid & 15, ol = (tid >> 4) & 3, cg = tid >> 6;
    const int o = ot * 4 + ol, f0 = ft * 16;

    for (int i = tid; i < 8192; i += 256) {
        int bh = i >> 11, c = (i >> 4) & 127, ff = i & 15;
        Stile[bh][c][ff] = S[(size_t)bh * 16384 + c * 128 + f0 + ff];
    }
    __syncthreads();

    float g0 = 0.f, g1 = 0.f, g2 = 0.f, g3 = 0.f;  // gre_b0, gmi_b0, gre_b1, gmi_b1
#pragma unroll 4
    for (int c = cg * 32; c < cg * 32 + 32; ++c) {
        float wr = Wre[((size_t)(c * 128 + o)) * 128 + f0 + fl];
        float wi = Wim[((size_t)(c * 128 + o)) * 128 + f0 + fl];
        float sc0 = Stile[0][c][fl], ss0 = Stile[1][c][fl];
        float sc1 = Stile[2][c][fl], ss1 = Stile[3][c][fl];
        g0 += sc0 * wr + ss0 * wi;  g1 += ss0 * wr - sc0 * wi;
        g2 += sc1 * wr + ss1 * wi;  g3 += ss1 * wr - sc1 * wi;
    }
    __syncthreads();
    float* red = (float*)Stile;                    // reuse: 4 cg x 64 (ol,fl) x 4 vals
    float4v* rp = (float4v*)red;
    rp[cg * 64 + ol * 16 + fl] = (float4v){g0, g1, g2, g3};
    __syncthreads();
    if (cg == 0) {
        float4v r = rp[ol * 16 + fl];
        r += rp[64 + ol * 16 + fl];
        r += rp[128 + ol * 16 + fl];
        r += rp[192 + ol * 16 + fl];
        const float invN = 1.0f / (float)Nn;
        float gre0 = r[0] * invN, gmi0 = r[1] * invN;
        float gre1 = r[2] * invN, gmi1 = r[3] * invN;
        Gh[(0 * 128 + o) * 128 + f0 + fl] = pack_hi(gre0, gmi0);
        Gl[(0 * 128 + o) * 128 + f0 + fl] = pack_hi(resid(gre0), resid(gmi0));
        Gh[(1 * 128 + o) * 128 + f0 + fl] = pack_hi(gre1, gmi1);
        Gl[(1 * 128 + o) * 128 + f0 + fl] = pack_hi(resid(gre1), resid(gmi1));
    }
}

// ---------------- inverse evaluation + gelu: barrier-free, zero-LDS, n-tile 64 (4 blocks/CU)
__global__ __launch_bounds__(256) void inv_bf(const uint_t* __restrict__ Gh,
                                              const uint_t* __restrict__ Gl,
                                              const float* __restrict__ ptsT,
                                              const float* __restrict__ freqs,
                                              float* __restrict__ hfT) {
    const int nt = blockIdx.x, b = blockIdx.y;
    const int n0 = nt * 64;
    const int tid = threadIdx.x, lane = tid & 63, wave = tid >> 6;
    const int wm = wave & 1, wn = wave >> 1;       // 2 n-halves x 2 o-halves
    const int fr = lane & 15, kg = lane >> 4;

    const float* pb = ptsT + ((size_t)(b * 3) << 15);
    float px[2], py[2], pz[2];
#pragma unroll
    for (int mi = 0; mi < 2; ++mi) {
        int n = n0 + wm * 32 + mi * 16 + fr;
        px[mi] = pb[n]; py[mi] = pb[(1 << 15) + n]; pz[mi] = pb[(2 << 15) + n];
    }

    float4v acc[2][4];
#pragma unroll
    for (int mi = 0; mi < 2; ++mi)
#pragma unroll
        for (int ni = 0; ni < 4; ++ni) acc[mi][ni] = (float4v){0.f, 0.f, 0.f, 0.f};

    for (int kt = 0; kt < 8; ++kt) {
        const int fbase = kt * 16 + kg * 4;
        float kxx[4], kyy[4], kzz[4];
#pragma unroll
        for (int q = 0; q < 4; ++q) {
            kxx[q] = TWOPI * freqs[(fbase + q) * 3 + 0];
            kyy[q] = TWOPI * freqs[(fbase + q) * 3 + 1];
            kzz[q] = TWOPI * freqs[(fbase + q) * 3 + 2];
        }
        frag_cast bh[4], bl[4];
#pragma unroll
        for (int ni = 0; ni < 4; ++ni) {
            size_t gi = ((size_t)(b * 128 + wn * 64 + ni * 16 + fr)) * 128 + fbase;
            bh[ni].s = *(const short8*)(Gh + gi);
            bl[ni].s = *(const short8*)(Gl + gi);
        }
#pragma unroll
        for (int mi = 0; mi < 2; ++mi) {
            frag_cast ah, al;
#pragma unroll
            for (int q = 0; q < 4; ++q) {
                float ang = px[mi] * kxx[q] + py[mi] * kyy[q] + pz[mi] * kzz[q];
                float cv = __cosf(ang), sv = __sinf(ang);
                ah.u[q] = pack_hi(cv, sv);
                al.u[q] = pack_hi(resid(cv), resid(sv));
            }
#pragma unroll
            for (int ni = 0; ni < 4; ++ni) {
                acc[mi][ni] = __builtin_amdgcn_mfma_f32_16x16x32_bf16(ah.s, bh[ni].s, acc[mi][ni], 0, 0, 0);
                acc[mi][ni] = __builtin_amdgcn_mfma_f32_16x16x32_bf16(ah.s, bl[ni].s, acc[mi][ni], 0, 0, 0);
                acc[mi][ni] = __builtin_amdgcn_mfma_f32_16x16x32_bf16(al.s, bh[ni].s, acc[mi][ni], 0, 0, 0);
            }
        }
    }

    // epilogue: gelu (tanh approx via expf) + 16B-contiguous transposed store
#pragma unroll
    for (int mi = 0; mi < 2; ++mi)
#pragma unroll
        for (int ni = 0; ni < 4; ++ni) {
            float4v gv;
#pragma unroll
            for (int r = 0; r < 4; ++r) {
                float v = acc[mi][ni][r];
                float u2 = 1.5957691216057308f * (v + 0.044715f * v * v * v);  // 2*sqrt(2/pi)*(...)
                float t = 1.0f - 2.0f / (1.0f + __expf(u2));                    // tanh
                gv[r] = 0.5f * v * (1.0f + t);
            }
            int o = wn * 64 + ni * 16 + fr;
            int n = n0 + wm * 32 + mi * 16 + kg * 4;
            *(float4v*)(hfT + (((size_t)(b * 128 + o)) << 15) + n) = gv;
        }
}

// ---------------- out projection (reads hfT)
__global__ __launch_bounds__(256) void out_proj(const float* __restrict__ hfT,
                                                const float* __restrict__ w,
                                                const float* __restrict__ bias,
                                                float* __restrict__ u) {
    int i = blockIdx.x * 256 + threadIdx.x;        // b*Nn + n
    int b = i >> 15, n = i & 32767;
    const float* hp = hfT + ((size_t)(b * 128) << 15) + n;
    float s0 = bias[0], s1 = bias[1];
#pragma unroll 8
    for (int c = 0; c < 128; ++c) {
        float h = hp[(size_t)c << 15];
        s0 += h * w[c * 2 + 0];
        s1 += h * w[c * 2 + 1];
    }
    u[(size_t)i * 2 + 0] = s0;
    u[(size_t)i * 2 + 1] = s1;
}

extern "C" void kernel_launch(void* const* d_in, const int* in_sizes, int n_in,
                              void* d_out, int out_size, void* d_ws, size_t ws_size,
                              hipStream_t stream) {
    const float* a        = (const float*)d_in[0];
    const float* x        = (const float*)d_in[1];
    const float* y        = (const float*)d_in[2];
    const float* fc_in_w  = (const float*)d_in[3];
    const float* fc_in_b  = (const float*)d_in[4];
    const float* freqs    = (const float*)d_in[5];
    const float* w_real   = (const float*)d_in[6];
    const float* w_imag   = (const float*)d_in[7];
    const float* fc_out_w = (const float*)d_in[8];
    const float* fc_out_b = (const float*)d_in[9];
    float* out = (float*)d_out;

    float*  ws    = (float*)d_ws;
    float*  hfT   = ws;                                        // B*C*N       = 8,388,608 floats
    float*  Spart = hfT + (size_t)Bb * Cc * Nn;                // B*2*SKN*C*F = 8,388,608
    float*  S     = Spart + (size_t)Bb * 2 * SKN * Cc * Ff;    // 65,536
    uint_t* Gh    = (uint_t*)(S + (size_t)Bb * 2 * Cc * Ff);   // 32,768 dwords
    uint_t* Gl    = Gh + (size_t)Bb * Cc * Ff;                 // 32,768 dwords
    float*  xT    = (float*)(Gl + (size_t)Bb * Cc * Ff);       // B*3*N = 196,608
    float*  yT    = xT + (size_t)Bb * 3 * Nn;                  // 196,608

    prep_xt<<<(Bb * Nn) / 256, 256, 0, stream>>>(x, y, xT, yT);
    in_proj<<<(Bb * Cc * Nn) / 256, 256, 0, stream>>>(a, fc_in_w, fc_in_b, hfT);

    for (int l = 0; l < LL; ++l) {
        const float* k   = freqs  + (size_t)l * Ff * 3;
        const float* Wre = w_real + (size_t)l * Cc * Cc * Ff;
        const float* Wim = w_imag + (size_t)l * Cc * Cc * Ff;
        const float* pT  = (l < LL - 1) ? xT : yT;

        fwd_bf<<<dim3(SKN, 2, Bb), 256, 0, stream>>>(hfT, xT, k, Spart);
        reduce_kernel<<<(Bb * 2 * Cc * Ff) / 256, 256, 0, stream>>>(Spart, S);
        mix_kernel<<<dim3(32, 8), 256, 0, stream>>>(S, Wre, Wim, Gh, Gl);
        inv_bf<<<dim3(Nn / 64, Bb), 256, 0, stream>>>(Gh, Gl, pT, k, hfT);
    }

    out_proj<<<(Bb * Nn) / 256, 256, 0, stream>>>(hfT, fc_out_w, fc_out_b, out);
}